// Round 3
// baseline (126.070 us; speedup 1.0000x reference)
//
#include <hip/hip_runtime.h>

// IndRNN forward: proj = x @ W + b  (M=B*T, K=D=256, N=U), then
// h_t = relu(proj_t + h_{t-1} * clip(u,0,1)) over T.
// R2: fused kernel per (b, 128-unit slice): x-chunk (64 t) staged to LDS
//     (XOR-swizzled), MFMA with W-frags resident in VGPRs, proj written back
//     into the same LDS buffer, scan overlapped with staging of next chunk.
// R3: uniform all-wave staging + explicit drain (fixed stale-A-tile race).
// R4: GN=64 / 2 blocks-per-CU experiment: EXACTLY neutral (122.15 vs 122.10)
//     -> fused kernel is not occupancy-bound; reverted to GN=128.
// R5: conv_x DELETED. Fused kernel reads fp32 x directly and reg-stages:
//     global_load_dwordx4 issued at top of iteration (latency hides under
//     MFMA), f2bf RNE convert (bit-identical to old conv_x), ds_write_b128
//     into the same swizzled layout. Per-lane LDS scatter is legal for
//     ds_write (no global_load_lds DMA left -> R3's race class is gone;
//     plain barrier lgkmcnt semantics cover staging visibility).
//     Saves conv_x's 201 MB HBM round-trip (~32 us) + one launch gap;
//     x re-reads (134 MB unique, x4 slices) are L3-absorbed.

__device__ __forceinline__ unsigned short f2bf(float f) {
    unsigned int u = __float_as_uint(f);
    unsigned int r = (u + 0x7FFF + ((u >> 16) & 1)) >> 16;  // RNE
    return (unsigned short)r;
}

typedef __bf16 bf16x8 __attribute__((ext_vector_type(8)));
typedef unsigned short u16x8 __attribute__((ext_vector_type(8)));
typedef float f32x4 __attribute__((ext_vector_type(4)));

// ------------------------------------------------------------ conversion
__global__ __launch_bounds__(256) void conv_wt(
    const float* __restrict__ W, unsigned short* __restrict__ Wt, int K, int N)
{
    int idx = blockIdx.x * blockDim.x + threadIdx.x;
    int kq = K >> 2;
    if (idx >= N * kq) return;
    int n = idx / kq;
    int k4 = (idx - n * kq) * 4;
    ushort4 o;
    o.x = f2bf(W[(long)(k4 + 0) * N + n]);
    o.y = f2bf(W[(long)(k4 + 1) * N + n]);
    o.z = f2bf(W[(long)(k4 + 2) * N + n]);
    o.w = f2bf(W[(long)(k4 + 3) * N + n]);
    *(ushort4*)(Wt + (long)n * K + k4) = o;
}

// ------------------------------------------------------------ fused kernel
// Requires D == 256, U % 128 == 0, T % 64 == 0.
#define TC 64    // timesteps per chunk
#define GN 128   // units per block

__global__ __launch_bounds__(256, 1) void indrnn_fused(
    const float* __restrict__ x,             // fp32 [B*T, 256]
    const unsigned short* __restrict__ wt,   // bf16 [U, 256]  (W^T)
    const float* __restrict__ bias,          // [U]
    const float* __restrict__ h0,            // [B, U]
    const float* __restrict__ uvec,          // [U]
    float* __restrict__ out,                 // [B, T, U]
    int B, int T, int U)
{
    __shared__ char X[2][TC * 512];          // 2 x 32 KB: bf16 A-chunk, then fp32 proj

    const int tid  = threadIdx.x;
    const int lane = tid & 63;
    const int w    = tid >> 6;     // wave 0..3
    const int m    = lane & 15;
    const int quad = lane >> 4;    // 0..3
    const int b    = blockIdx.x;
    const int n0   = blockIdx.y * GN;
    const int tq   = (w >> 1) * 32;   // wave's row quadrant (t-local)
    const int cq   = (w & 1) * 64;    // wave's col quadrant

    // W fragments resident in registers: 4 col-tiles x 8 k-steps x 16B = 128 VGPRs.
    // B-frag layout (proven): n = tile + m, k = kt*32 + quad*8 + e.
    bf16x8 bfr[4][8];
#pragma unroll
    for (int j = 0; j < 4; ++j)
#pragma unroll
        for (int kt = 0; kt < 8; ++kt)
            bfr[j][kt] = *(const bf16x8*)(
                wt + (long)(n0 + cq + j * 16 + m) * 256 + kt * 32 + quad * 8);

    float bb[4];
#pragma unroll
    for (int j = 0; j < 4; ++j) bb[j] = bias[n0 + cq + j * 16 + m];

    float uc = 0.0f, h = 0.0f;
    if (tid < GN) {
        uc = fminf(fmaxf(uvec[n0 + tid], 0.0f), 1.0f);
        h  = h0[(long)b * U + n0 + tid];
    }

    const float* xbase = x + (long)b * T * 256;

    // Staging decomposition: piece = 8 consecutive d (32 B fp32 -> 16 B bf16).
    // 32 pieces/row x 64 rows = 2048 pieces; thread handles piece
    // (srow + 8*i, spos) for i = 0..7. Consecutive lanes -> consecutive 32 B
    // global (coalesced); LDS chunk index = spos ^ (row & 15) (reader-proven
    // swizzle), 32 lanes cover one permuted 512 B row -> conflict-free b128.
    const int srow = tid >> 5;   // 0..7
    const int spos = tid & 31;   // 0..31

    // ---- prologue: stage chunk 0 (all threads, uniform)
    {
        float4 ra[8], rb[8];
#pragma unroll
        for (int i = 0; i < 8; ++i) {
            const float* g = xbase + (srow + 8 * i) * 256 + spos * 8;
            ra[i] = *(const float4*)g;
            rb[i] = *(const float4*)(g + 4);
        }
#pragma unroll
        for (int i = 0; i < 8; ++i) {
            int row = srow + 8 * i;
            int q   = spos ^ (row & 15);
            u16x8 o;
            o[0] = f2bf(ra[i].x); o[1] = f2bf(ra[i].y);
            o[2] = f2bf(ra[i].z); o[3] = f2bf(ra[i].w);
            o[4] = f2bf(rb[i].x); o[5] = f2bf(rb[i].y);
            o[6] = f2bf(rb[i].z); o[7] = f2bf(rb[i].w);
            *(u16x8*)(&X[0][row * 512 + q * 16]) = o;
        }
    }

    const int nch = T / TC;
    for (int c = 0; c < nch; ++c) {
        char* Xc = X[c & 1];
        __syncthreads();   // staging of chunk c visible (barrier drains lgkm)

        // ---- issue global loads for chunk c+1 NOW; latency hides under MFMA
        float4 ra[8], rb[8];
        const bool more = (c + 1 < nch);
        if (more) {
            const float* gb = xbase + (long)(c + 1) * TC * 256;
#pragma unroll
            for (int i = 0; i < 8; ++i) {
                const float* g = gb + (srow + 8 * i) * 256 + spos * 8;
                ra[i] = *(const float4*)g;
                rb[i] = *(const float4*)(g + 4);
            }
        }

        // ---- MFMA: wave computes 32t x 64u quadrant; A from LDS, B from regs
        f32x4 acc[2][4];
#pragma unroll
        for (int i = 0; i < 2; ++i)
#pragma unroll
            for (int j = 0; j < 4; ++j) acc[i][j] = (f32x4){0.f, 0.f, 0.f, 0.f};

#pragma unroll
        for (int kt = 0; kt < 8; ++kt) {
            const int off = (((kt * 4 + quad) ^ m) * 16);
            bf16x8 a0 = *(const bf16x8*)(Xc + (tq + m) * 512 + off);
            bf16x8 a1 = *(const bf16x8*)(Xc + (tq + 16 + m) * 512 + off);
#pragma unroll
            for (int j = 0; j < 4; ++j) {
                acc[0][j] = __builtin_amdgcn_mfma_f32_16x16x32_bf16(
                    a0, bfr[j][kt], acc[0][j], 0, 0, 0);
                acc[1][j] = __builtin_amdgcn_mfma_f32_16x16x32_bf16(
                    a1, bfr[j][kt], acc[1][j], 0, 0, 0);
            }
        }
        __syncthreads();   // all reads of Xc done

        // ---- convert + ds_write chunk c+1 into the other buffer.
        // X[(c+1)&1] was last read by the scan of chunk c-1, which completed
        // before this iteration's top barrier -> safe to overwrite.
        if (more) {
            char* Xn = X[(c + 1) & 1];
#pragma unroll
            for (int i = 0; i < 8; ++i) {
                int row = srow + 8 * i;
                int q   = spos ^ (row & 15);
                u16x8 o;
                o[0] = f2bf(ra[i].x); o[1] = f2bf(ra[i].y);
                o[2] = f2bf(ra[i].z); o[3] = f2bf(ra[i].w);
                o[4] = f2bf(rb[i].x); o[5] = f2bf(rb[i].y);
                o[6] = f2bf(rb[i].z); o[7] = f2bf(rb[i].w);
                *(u16x8*)(Xn + row * 512 + q * 16) = o;
            }
        }

        // ---- proj (+bias) -> same LDS buffer Xc, fp32, col-swizzled by quad
        float* pf = (float*)Xc;
#pragma unroll
        for (int i = 0; i < 2; ++i)
#pragma unroll
            for (int j = 0; j < 4; ++j)
#pragma unroll
                for (int r = 0; r < 4; ++r) {
                    int tl  = tq + i * 16 + quad * 4 + r;
                    int col = cq + j * 16 + m;
                    int cs  = col ^ (quad << 4);   // quad == (tl>>2)&3
                    pf[tl * GN + cs] = acc[i][j][r] + bb[j];
                }
        __syncthreads();   // proj visible; staging writes also drained

        // ---- waves 0-1: sequential scan of chunk c (cols = tid)
        if (tid < GN) {
            const float* pfr = (const float*)Xc;
            float* og = out + ((long)b * T + c * TC) * U + n0 + tid;
#pragma unroll 8
            for (int t = 0; t < TC; ++t) {
                float pv = pfr[t * GN + (tid ^ (((t >> 2) & 3) << 4))];
                h = fmaxf(fmaf(h, uc, pv), 0.0f);
                og[(long)t * U] = h;
            }
        }
    }
}

// ------------------------------------------------------------ fp32 fallback
#define BM 128
#define BN 128
#define BK 8

__global__ __launch_bounds__(256) void indrnn_gemm_bias(
    const float* __restrict__ A, const float* __restrict__ Bm,
    const float* __restrict__ bias, float* __restrict__ C,
    int M, int N, int K)
{
    __shared__ float As[BK][BM];
    __shared__ float Bs[BK][BN];
    const int tid = threadIdx.x;
    const int row0 = blockIdx.x * BM, col0 = blockIdx.y * BN;
    const int tx = tid & 15, ty = tid >> 4;
    float acc[8][8];
#pragma unroll
    for (int i = 0; i < 8; ++i)
#pragma unroll
        for (int j = 0; j < 8; ++j) acc[i][j] = 0.0f;
    const int am = tid >> 1, ak = (tid & 1) * 4;
    const int bk = tid >> 5, bn = (tid & 31) * 4;
    const float* Aptr = A + (long)(row0 + am) * K + ak;
    const float* Bptr = Bm + (long)bk * N + col0 + bn;
    for (int kt = 0; kt < K; kt += BK) {
        float4 av = *(const float4*)(Aptr + kt);
        float4 bv = *(const float4*)(Bptr + (long)kt * N);
        As[ak + 0][am] = av.x; As[ak + 1][am] = av.y;
        As[ak + 2][am] = av.z; As[ak + 3][am] = av.w;
        *(float4*)&Bs[bk][bn] = bv;
        __syncthreads();
#pragma unroll
        for (int k = 0; k < BK; ++k) {
            float4 a0 = *(const float4*)&As[k][ty * 4];
            float4 a1 = *(const float4*)&As[k][64 + ty * 4];
            float4 b0 = *(const float4*)&Bs[k][tx * 4];
            float4 b1 = *(const float4*)&Bs[k][64 + tx * 4];
            float a[8] = {a0.x, a0.y, a0.z, a0.w, a1.x, a1.y, a1.z, a1.w};
            float bb2[8] = {b0.x, b0.y, b0.z, b0.w, b1.x, b1.y, b1.z, b1.w};
#pragma unroll
            for (int i = 0; i < 8; ++i)
#pragma unroll
                for (int j = 0; j < 8; ++j)
                    acc[i][j] = fmaf(a[i], bb2[j], acc[i][j]);
        }
        __syncthreads();
    }
    float bb[8];
#pragma unroll
    for (int j = 0; j < 4; ++j) {
        bb[j] = bias[col0 + tx * 4 + j];
        bb[j + 4] = bias[col0 + 64 + tx * 4 + j];
    }
#pragma unroll
    for (int i = 0; i < 8; ++i) {
        const int r = (i < 4) ? (ty * 4 + i) : (64 + ty * 4 + (i - 4));
        float* crow = C + (long)(row0 + r) * N + col0;
        float4 v0 = {acc[i][0] + bb[0], acc[i][1] + bb[1], acc[i][2] + bb[2], acc[i][3] + bb[3]};
        float4 v1 = {acc[i][4] + bb[4], acc[i][5] + bb[5], acc[i][6] + bb[6], acc[i][7] + bb[7]};
        *(float4*)(crow + tx * 4) = v0;
        *(float4*)(crow + 64 + tx * 4) = v1;
    }
}

#define SCAN_UNROLL 32

__global__ __launch_bounds__(256) void indrnn_scan(
    float* __restrict__ out, const float* __restrict__ h0,
    const float* __restrict__ u, int B, int T, int U)
{
    const int idx = blockIdx.x * blockDim.x + threadIdx.x;
    if (idx >= B * U) return;
    const int b = idx / U;
    const int un = idx - b * U;
    const float uc = fminf(fmaxf(u[un], 0.0f), 1.0f);
    float h = h0[(long)b * U + un];
    float* p = out + (long)b * T * U + un;
    for (int t = 0; t < T; t += SCAN_UNROLL) {
        float pv[SCAN_UNROLL];
#pragma unroll
        for (int i = 0; i < SCAN_UNROLL; ++i)
            pv[i] = p[(long)(t + i) * U];
#pragma unroll
        for (int i = 0; i < SCAN_UNROLL; ++i) {
            h = fmaxf(fmaf(h, uc, pv[i]), 0.0f);
            pv[i] = h;
        }
#pragma unroll
        for (int i = 0; i < SCAN_UNROLL; ++i)
            p[(long)(t + i) * U] = pv[i];
    }
}

// ------------------------------------------------------------ launch
extern "C" void kernel_launch(void* const* d_in, const int* in_sizes, int n_in,
                              void* d_out, int out_size, void* d_ws, size_t ws_size,
                              hipStream_t stream) {
    const float* x  = (const float*)d_in[0]; // [B,T,D]
    const float* h0 = (const float*)d_in[1]; // [B,U]
    const float* W  = (const float*)d_in[2]; // [D,U]
    const float* u  = (const float*)d_in[3]; // [U]
    const float* b  = (const float*)d_in[4]; // [U]
    float* out = (float*)d_out;              // [B,T,U]

    const int U = in_sizes[3];
    const int B = in_sizes[1] / U;
    const int D = in_sizes[2] / U;
    const int T = in_sizes[0] / (B * D);
    const int M = B * T;

    const size_t wt_bytes = (size_t)U * D * sizeof(unsigned short);
    const bool fused_ok = (D == 256) && (U % GN == 0) && (T % TC == 0) &&
                          (ws_size >= wt_bytes);

    if (fused_ok) {
        unsigned short* wt = (unsigned short*)d_ws;

        const int nwt = U * (D / 4);
        conv_wt<<<(nwt + 255) / 256, 256, 0, stream>>>(W, wt, D, U);

        dim3 g(B, U / GN);
        indrnn_fused<<<g, 256, 0, stream>>>(x, wt, b, h0, u, out, B, T, U);
    } else {
        dim3 ggrid(M / BM, U / BN);
        indrnn_gemm_bias<<<ggrid, 256, 0, stream>>>(x, W, b, out, M, U, D);
        const int nthreads = B * U;
        indrnn_scan<<<(nthreads + 255) / 256, 256, 0, stream>>>(out, h0, u, B, T, U);
    }
}

// Round 4
// 118.679 us; speedup vs baseline: 1.0623x; 1.0623x over previous
//
#include <hip/hip_runtime.h>

// IndRNN forward: proj = x @ W + b  (M=B*T, K=D=256, N=U), then
// h_t = relu(proj_t + h_{t-1} * clip(u,0,1)) over T.
// R2: fused kernel per (b, 128-unit slice): x-chunk (64 t) staged to LDS
//     (XOR-swizzled) via global_load_lds w=16, MFMA with W-frags in VGPRs.
// R3: uniform all-wave staging + explicit vmcnt drain (fixed staging race).
// R4: 2 blocks/CU experiment: neutral -> not occupancy-bound.
// R5: in-kernel fp32 staging+convert: fused 31->45 us (cvt VALU + 2x x bytes).
//     REVERTED: conv_x (bf16 pre-convert) + gl_lds staging restored.
// R6: structural de-serialization of the fused kernel:
//     (a) separate 32 KB proj buffer P -> proj no longer overwrites the
//         A-buffer -> one barrier per chunk ELIMINATED (3 -> 2), and a
//         single 32 KB A-buffer suffices (DMA for c+1 issued after the
//         sync that ends MFMA(c)'s reads; its latency hides under scan).
//     (b) proj stored TRANSPOSED P[u][t] fp32 with the G4 16B-granule XOR
//         swizzle (granule ^= u&7; identical formula on both sides):
//         scan = 16 x ds_read_b128 (issued upfront, no per-t addr VALU)
//         instead of 64 x ds_read_b32; proj-write = 8 x ds_write_b128
//         per wave. Both sides at the 2-way-free bank floor.

__device__ __forceinline__ unsigned short f2bf(float f) {
    unsigned int u = __float_as_uint(f);
    unsigned int r = (u + 0x7FFF + ((u >> 16) & 1)) >> 16;  // RNE
    return (unsigned short)r;
}

typedef __bf16 bf16x8 __attribute__((ext_vector_type(8)));
typedef float f32x4 __attribute__((ext_vector_type(4)));

typedef const unsigned char __attribute__((address_space(1))) gc_t;
typedef unsigned char __attribute__((address_space(3))) lds_t;

__device__ __forceinline__ void gl_lds16(const void* g, void* l) {
    __builtin_amdgcn_global_load_lds((gc_t*)g, (lds_t*)l, 16, 0, 0);
}

// ------------------------------------------------------------ conversion
__global__ __launch_bounds__(256) void conv_x(
    const float* __restrict__ x, unsigned short* __restrict__ xb, int n4)
{
    int i = blockIdx.x * blockDim.x + threadIdx.x;
    if (i >= n4) return;
    float4 v = *(const float4*)(x + (long)i * 4);
    ushort4 o;
    o.x = f2bf(v.x); o.y = f2bf(v.y); o.z = f2bf(v.z); o.w = f2bf(v.w);
    *(ushort4*)(xb + (long)i * 4) = o;
}

__global__ __launch_bounds__(256) void conv_wt(
    const float* __restrict__ W, unsigned short* __restrict__ Wt, int K, int N)
{
    int idx = blockIdx.x * blockDim.x + threadIdx.x;
    int kq = K >> 2;
    if (idx >= N * kq) return;
    int n = idx / kq;
    int k4 = (idx - n * kq) * 4;
    ushort4 o;
    o.x = f2bf(W[(long)(k4 + 0) * N + n]);
    o.y = f2bf(W[(long)(k4 + 1) * N + n]);
    o.z = f2bf(W[(long)(k4 + 2) * N + n]);
    o.w = f2bf(W[(long)(k4 + 3) * N + n]);
    *(ushort4*)(Wt + (long)n * K + k4) = o;
}

// ------------------------------------------------------------ fused kernel
// Requires D == 256, U % 128 == 0, T % 64 == 0.
#define TC 64    // timesteps per chunk
#define GN 128   // units per block

__global__ __launch_bounds__(256, 1) void indrnn_fused(
    const unsigned short* __restrict__ xb,   // bf16 [B*T, 256]
    const unsigned short* __restrict__ wt,   // bf16 [U, 256]  (W^T)
    const float* __restrict__ bias,          // [U]
    const float* __restrict__ h0,            // [B, U]
    const float* __restrict__ uvec,          // [U]
    float* __restrict__ out,                 // [B, T, U]
    int B, int T, int U)
{
    __shared__ char Xs[TC * 512];            // 32 KB: bf16 A-chunk (single buffer)
    __shared__ char Ps[GN * TC * 4];         // 32 KB: fp32 proj, TRANSPOSED [u][t]

    const int tid  = threadIdx.x;
    const int lane = tid & 63;
    const int w    = tid >> 6;     // wave 0..3
    const int m    = lane & 15;
    const int quad = lane >> 4;    // 0..3
    const int b    = blockIdx.x;
    const int n0   = blockIdx.y * GN;
    const int tq   = (w >> 1) * 32;   // wave's row quadrant (t-local)
    const int cq   = (w & 1) * 64;    // wave's col quadrant

    // W fragments resident in registers: 4 col-tiles x 8 k-steps x 16B = 128 VGPRs.
    // B-frag layout (proven): n = tile + m, k = kt*32 + quad*8 + e.
    bf16x8 bfr[4][8];
#pragma unroll
    for (int j = 0; j < 4; ++j)
#pragma unroll
        for (int kt = 0; kt < 8; ++kt)
            bfr[j][kt] = *(const bf16x8*)(
                wt + (long)(n0 + cq + j * 16 + m) * 256 + kt * 32 + quad * 8);

    float bb[4];
#pragma unroll
    for (int j = 0; j < 4; ++j) bb[j] = bias[n0 + cq + j * 16 + m];

    float uc = 0.0f, h = 0.0f;
    if (tid < GN) {
        uc = fminf(fmaxf(uvec[n0 + tid], 0.0f), 1.0f);
        h  = h0[(long)b * U + n0 + tid];
    }

    const unsigned short* xrow = xb + (long)b * T * 256;
    const int p  = lane & 31;
    const int hh = lane >> 5;

    // ---- prologue: stage chunk 0 (all 4 waves, 8 x 1KB calls each).
    // LDS[row][pos] <- global granule (pos ^ (row&15))  [16B granules, 32/row]
#pragma unroll
    for (int i = 0; i < 8; ++i) {
        int blk = i * 4 + w;          // 1KB block = 2 rows
        int row = blk * 2 + hh;
        int gp  = p ^ (row & 15);
        gl_lds16(xrow + (long)row * 256 + gp * 8, &Xs[blk * 1024]);
    }
    asm volatile("s_waitcnt vmcnt(0)" ::: "memory");
    __builtin_amdgcn_sched_barrier(0);
    __syncthreads();   // chunk 0 staged & visible

    const int nch = T / TC;
    for (int c = 0; c < nch; ++c) {
        // ---- MFMA: wave computes 32t x 64u quadrant; A from LDS, B from regs
        f32x4 acc[2][4];
#pragma unroll
        for (int i = 0; i < 2; ++i)
#pragma unroll
            for (int j = 0; j < 4; ++j) acc[i][j] = (f32x4){0.f, 0.f, 0.f, 0.f};

#pragma unroll
        for (int kt = 0; kt < 8; ++kt) {
            const int off = (((kt * 4 + quad) ^ m) * 16);
            bf16x8 a0 = *(const bf16x8*)(Xs + (tq + m) * 512 + off);
            bf16x8 a1 = *(const bf16x8*)(Xs + (tq + 16 + m) * 512 + off);
#pragma unroll
            for (int j = 0; j < 4; ++j) {
                acc[0][j] = __builtin_amdgcn_mfma_f32_16x16x32_bf16(
                    a0, bfr[j][kt], acc[0][j], 0, 0, 0);
                acc[1][j] = __builtin_amdgcn_mfma_f32_16x16x32_bf16(
                    a1, bfr[j][kt], acc[1][j], 0, 0, 0);
            }
        }

        // ---- proj (+bias) -> P, TRANSPOSED [u][t], fp32, b128 writes.
        // Granule swizzle (G4 recipe): granule g = tl>>2; stored at
        // byte = col*256 + ((g ^ (col&7)) << 4). acc[i][j] holds 4
        // consecutive t (r=0..3) for one col -> exactly one f32x4 write.
#pragma unroll
        for (int i = 0; i < 2; ++i)
#pragma unroll
            for (int j = 0; j < 4; ++j) {
                f32x4 v = acc[i][j];
                f32x4 vb = {v[0] + bb[j], v[1] + bb[j], v[2] + bb[j], v[3] + bb[j]};
                int col = cq + j * 16 + m;
                int g   = (tq >> 2) + i * 4 + quad;   // tl0>>2, tl0 = tq+i*16+quad*4
                *(f32x4*)(Ps + col * 256 + (((g ^ (col & 7)) << 4))) = vb;
            }
        __syncthreads();   // proj visible; all MFMA reads of Xs done block-wide

        // ---- issue staging of chunk c+1 into Xs (uniform, all 4 waves).
        // Safe: every wave's MFMA reads of Xs completed before the barrier.
        // DMA latency hides under the scan; drained before the next barrier.
        if (c + 1 < nch) {
            const unsigned short* gb = xrow + (long)(c + 1) * TC * 256;
#pragma unroll
            for (int i = 0; i < 8; ++i) {
                int blk = i * 4 + w;
                int row = blk * 2 + hh;
                int gp  = p ^ (row & 15);
                gl_lds16(gb + (long)row * 256 + gp * 8, &Xs[blk * 1024]);
            }
        }

        // ---- waves 0-1: sequential scan of chunk c from P (b128 reads)
        if (tid < GN) {
            f32x4 pv[16];
            const int ub = tid * 256;
            const int ux = (tid & 7) << 4;
#pragma unroll
            for (int gg = 0; gg < 16; ++gg)
                pv[gg] = *(const f32x4*)(Ps + ub + ((gg << 4) ^ ux));
            float* og = out + ((long)b * T + c * TC) * U + n0 + tid;
#pragma unroll
            for (int gg = 0; gg < 16; ++gg)
#pragma unroll
                for (int e = 0; e < 4; ++e) {
                    h = fmaxf(fmaf(h, uc, pv[gg][e]), 0.0f);
                    og[(long)(gg * 4 + e) * U] = h;
                }
        }

        // ---- drain staging DMA explicitly, then barrier (R3 race fix).
        asm volatile("s_waitcnt vmcnt(0)" ::: "memory");
        __builtin_amdgcn_sched_barrier(0);
        __syncthreads();   // chunk c+1 staged; P free for next proj
    }
}

// ------------------------------------------------------------ fp32 fallback
#define BM 128
#define BN 128
#define BK 8

__global__ __launch_bounds__(256) void indrnn_gemm_bias(
    const float* __restrict__ A, const float* __restrict__ Bm,
    const float* __restrict__ bias, float* __restrict__ C,
    int M, int N, int K)
{
    __shared__ float As[BK][BM];
    __shared__ float Bs[BK][BN];
    const int tid = threadIdx.x;
    const int row0 = blockIdx.x * BM, col0 = blockIdx.y * BN;
    const int tx = tid & 15, ty = tid >> 4;
    float acc[8][8];
#pragma unroll
    for (int i = 0; i < 8; ++i)
#pragma unroll
        for (int j = 0; j < 8; ++j) acc[i][j] = 0.0f;
    const int am = tid >> 1, ak = (tid & 1) * 4;
    const int bk = tid >> 5, bn = (tid & 31) * 4;
    const float* Aptr = A + (long)(row0 + am) * K + ak;
    const float* Bptr = Bm + (long)bk * N + col0 + bn;
    for (int kt = 0; kt < K; kt += BK) {
        float4 av = *(const float4*)(Aptr + kt);
        float4 bv = *(const float4*)(Bptr + (long)kt * N);
        As[ak + 0][am] = av.x; As[ak + 1][am] = av.y;
        As[ak + 2][am] = av.z; As[ak + 3][am] = av.w;
        *(float4*)&Bs[bk][bn] = bv;
        __syncthreads();
#pragma unroll
        for (int k = 0; k < BK; ++k) {
            float4 a0 = *(const float4*)&As[k][ty * 4];
            float4 a1 = *(const float4*)&As[k][64 + ty * 4];
            float4 b0 = *(const float4*)&Bs[k][tx * 4];
            float4 b1 = *(const float4*)&Bs[k][64 + tx * 4];
            float a[8] = {a0.x, a0.y, a0.z, a0.w, a1.x, a1.y, a1.z, a1.w};
            float bb2[8] = {b0.x, b0.y, b0.z, b0.w, b1.x, b1.y, b1.z, b1.w};
#pragma unroll
            for (int i = 0; i < 8; ++i)
#pragma unroll
                for (int j = 0; j < 8; ++j)
                    acc[i][j] = fmaf(a[i], bb2[j], acc[i][j]);
        }
        __syncthreads();
    }
    float bb[8];
#pragma unroll
    for (int j = 0; j < 4; ++j) {
        bb[j] = bias[col0 + tx * 4 + j];
        bb[j + 4] = bias[col0 + 64 + tx * 4 + j];
    }
#pragma unroll
    for (int i = 0; i < 8; ++i) {
        const int r = (i < 4) ? (ty * 4 + i) : (64 + ty * 4 + (i - 4));
        float* crow = C + (long)(row0 + r) * N + col0;
        float4 v0 = {acc[i][0] + bb[0], acc[i][1] + bb[1], acc[i][2] + bb[2], acc[i][3] + bb[3]};
        float4 v1 = {acc[i][4] + bb[4], acc[i][5] + bb[5], acc[i][6] + bb[6], acc[i][7] + bb[7]};
        *(float4*)(crow + tx * 4) = v0;
        *(float4*)(crow + 64 + tx * 4) = v1;
    }
}

#define SCAN_UNROLL 32

__global__ __launch_bounds__(256) void indrnn_scan(
    float* __restrict__ out, const float* __restrict__ h0,
    const float* __restrict__ u, int B, int T, int U)
{
    const int idx = blockIdx.x * blockDim.x + threadIdx.x;
    if (idx >= B * U) return;
    const int b = idx / U;
    const int un = idx - b * U;
    const float uc = fminf(fmaxf(u[un], 0.0f), 1.0f);
    float h = h0[(long)b * U + un];
    float* p = out + (long)b * T * U + un;
    for (int t = 0; t < T; t += SCAN_UNROLL) {
        float pv[SCAN_UNROLL];
#pragma unroll
        for (int i = 0; i < SCAN_UNROLL; ++i)
            pv[i] = p[(long)(t + i) * U];
#pragma unroll
        for (int i = 0; i < SCAN_UNROLL; ++i) {
            h = fmaxf(fmaf(h, uc, pv[i]), 0.0f);
            pv[i] = h;
        }
#pragma unroll
        for (int i = 0; i < SCAN_UNROLL; ++i)
            p[(long)(t + i) * U] = pv[i];
    }
}

// ------------------------------------------------------------ launch
extern "C" void kernel_launch(void* const* d_in, const int* in_sizes, int n_in,
                              void* d_out, int out_size, void* d_ws, size_t ws_size,
                              hipStream_t stream) {
    const float* x  = (const float*)d_in[0]; // [B,T,D]
    const float* h0 = (const float*)d_in[1]; // [B,U]
    const float* W  = (const float*)d_in[2]; // [D,U]
    const float* u  = (const float*)d_in[3]; // [U]
    const float* b  = (const float*)d_in[4]; // [U]
    float* out = (float*)d_out;              // [B,T,U]

    const int U = in_sizes[3];
    const int B = in_sizes[1] / U;
    const int D = in_sizes[2] / U;
    const int T = in_sizes[0] / (B * D);
    const int M = B * T;

    const size_t xb_bytes = (size_t)M * D * sizeof(unsigned short);
    const size_t wt_bytes = (size_t)U * D * sizeof(unsigned short);
    const bool fused_ok = (D == 256) && (U % GN == 0) && (T % TC == 0) &&
                          (ws_size >= xb_bytes + wt_bytes);

    if (fused_ok) {
        unsigned short* xb = (unsigned short*)d_ws;
        unsigned short* wt = (unsigned short*)((char*)d_ws + xb_bytes);

        const int n4 = (M * D) / 4;
        conv_x<<<(n4 + 255) / 256, 256, 0, stream>>>(x, xb, n4);
        const int nwt = U * (D / 4);
        conv_wt<<<(nwt + 255) / 256, 256, 0, stream>>>(W, wt, D, U);

        dim3 g(B, U / GN);
        indrnn_fused<<<g, 256, 0, stream>>>(xb, wt, b, h0, u, out, B, T, U);
    } else {
        dim3 ggrid(M / BM, U / BN);
        indrnn_gemm_bias<<<ggrid, 256, 0, stream>>>(x, W, b, out, M, U, D);
        const int nthreads = B * U;
        indrnn_scan<<<(nthreads + 255) / 256, 256, 0, stream>>>(out, h0, u, B, T, U);
    }
}